// Round 5
// baseline (328.664 us; speedup 1.0000x reference)
//
#include <hip/hip_runtime.h>
#include <stdint.h>
#include <math.h>

#define B_ 16
#define N_ 16
#define H_ 640
#define W_ 640
#define PH_ 300
#define PW_ 300

#define IMG_ELEMS (H_*W_*3)        // 1228800
#define IMG_F4    (IMG_ELEMS/4)    // 307200
#define PATCH_ELEMS (PH_*PW_*3)    // 270000

typedef float fx4 __attribute__((ext_vector_type(4)));

// ---------------- JAX Threefry-2x32-20, bit-exact ----------------
__device__ __forceinline__ uint2 tf2x32(uint32_t k0, uint32_t k1, uint32_t x0, uint32_t x1) {
  uint32_t k2 = k0 ^ k1 ^ 0x1BD11BDAu;
#define TFR(r) x0 += x1; x1 = (x1 << (r)) | (x1 >> (32 - (r))); x1 ^= x0;
  x0 += k0; x1 += k1;
  TFR(13) TFR(15) TFR(26) TFR(6)
  x0 += k1; x1 += k2 + 1u;
  TFR(17) TFR(29) TFR(16) TFR(24)
  x0 += k2; x1 += k0 + 2u;
  TFR(13) TFR(15) TFR(26) TFR(6)
  x0 += k0; x1 += k1 + 3u;
  TFR(17) TFR(29) TFR(16) TFR(24)
  x0 += k1; x1 += k2 + 4u;
  TFR(13) TFR(15) TFR(26) TFR(6)
  x0 += k2; x1 += k0 + 5u;
#undef TFR
  return make_uint2(x0, x1);
}

// jax_threefry_partitionable=True (default since jax 0.4.30):
//  - split(key, n):   key_i = (out.x, out.y) of tf(key, (0, i))
//  - random_bits(key, 32, shape): elem_i = out.x ^ out.y of tf(key, (0, i))
__device__ __forceinline__ uint32_t rb32(uint32_t k0, uint32_t k1, uint32_t i) {
  uint2 o = tf2x32(k0, k1, 0u, i);
  return o.x ^ o.y;
}

__device__ __forceinline__ float u01f(uint32_t bits) {
  return __uint_as_float((bits >> 9) | 0x3F800000u) - 1.0f;
}

// XLA f32 ErfInv (Giles polynomial) — matches lax.erf_inv
__device__ __forceinline__ float erfinv32(float x) {
  float w = -log1pf(-x * x);
  float p;
  if (w < 5.0f) {
    w = w - 2.5f;
    p = 2.81022636e-08f;
    p = fmaf(p, w, 3.43273939e-07f);
    p = fmaf(p, w, -3.5233877e-06f);
    p = fmaf(p, w, -4.39150654e-06f);
    p = fmaf(p, w, 0.00021858087f);
    p = fmaf(p, w, -0.00125372503f);
    p = fmaf(p, w, -0.00417768164f);
    p = fmaf(p, w, 0.246640727f);
    p = fmaf(p, w, 1.50140941f);
  } else {
    w = sqrtf(w) - 3.0f;
    p = -0.000200214257f;
    p = fmaf(p, w, 0.000100950558f);
    p = fmaf(p, w, 0.00134934322f);
    p = fmaf(p, w, -0.00367342844f);
    p = fmaf(p, w, 0.00573950773f);
    p = fmaf(p, w, -0.0076224613f);
    p = fmaf(p, w, 0.00943887047f);
    p = fmaf(p, w, 1.00167406f);
    p = fmaf(p, w, 2.83297682f);
  }
  return p * x;
}

// jax.random.normal: u ~ uniform(nextafter(-1,0), 1), sqrt(2)*erfinv(u)
__device__ __forceinline__ float jnormal(uint32_t bits) {
  float lo = __uint_as_float(0xBF7FFFFFu);  // nextafterf(-1,0)
  float span = 1.0f - lo;                   // rounds to 2.0f, same as XLA
  float u = fmaxf(lo, u01f(bits) * span + lo);
  return 1.4142135623730951f * erfinv32(u);
}

// ---------------- per-(image,box) parameters ----------------
// params[t*16]: 0 y0i, 1 x0i, 2 diagi, 3 phi, 4 c, 5 ca, 6 sa, 7 top,
//               8 bright, 9 300/phi, 10 unused, 11 valid, 12 k2a, 13 k2b
__global__ void setup_kernel(const float* __restrict__ boxes, const float* __restrict__ scale_p,
                             float* __restrict__ params, float* __restrict__ wb) {
  int t = threadIdx.x;
  if (t >= B_*N_) return;
  int b = t >> 4, n = t & 15;
  uint2 kb = tf2x32(0u, 42u, 0u, (uint32_t)b);
  uint2 kw  = tf2x32(kb.x, kb.y, 0u, 0u);
  uint2 kbk = tf2x32(kb.x, kb.y, 0u, 1u);
  uint2 kl  = tf2x32(kb.x, kb.y, 0u, 2u);
  if (n == 0) {
    wb[b*8+0] = jnormal(rb32(kw.x,  kw.y,  0u)) * 0.1f + 0.5f;
    wb[b*8+1] = jnormal(rb32(kw.x,  kw.y,  1u)) * 0.1f + 0.5f;
    wb[b*8+2] = jnormal(rb32(kw.x,  kw.y,  2u)) * 0.1f + 0.5f;
    wb[b*8+3] = jnormal(rb32(kbk.x, kbk.y, 0u)) * 0.01f;
    wb[b*8+4] = jnormal(rb32(kbk.x, kbk.y, 1u)) * 0.01f;
    wb[b*8+5] = jnormal(rb32(kbk.x, kbk.y, 2u)) * 0.01f;
  }
  uint2 kk = tf2x32(kl.x, kl.y, 0u, (uint32_t)n);
  uint2 k1 = tf2x32(kk.x, kk.y, 0u, 0u);
  uint2 k2 = tf2x32(kk.x, kk.y, 0u, 1u);
  uint2 k3 = tf2x32(kk.x, kk.y, 0u, 2u);
  const float MA = (float)(20.0 * 3.14159265358979323846 / 180.0);
  float angle  = fmaxf(-MA,   u01f(rb32(k1.x, k1.y, 0u)) * (MA - (-MA)) + (-MA));
  float bright = fmaxf(-0.3f, u01f(rb32(k3.x, k3.y, 0u)) * (0.3f - (-0.3f)) + (-0.3f));

  const float* bx = boxes + (size_t)t * 4;
  float ymin = bx[0], xmin = bx[1], ymax = bx[2], xmax = bx[3];
  float sc = scale_p[0];
  float h = ymax - ymin, ww = xmax - xmin;
  float longer = fmaxf(h, ww);
  float ps = floorf(longer * sc);
  float diag = fminf(sqrtf(2.0f) * ps, (float)W_);
  float oy = ymin + h * 0.5f;
  float ox = xmin + ww * 0.5f;
  float y0 = fmaxf(oy - diag * 0.5f, 0.0f);
  float x0 = fmaxf(ox - diag * 0.5f, 0.0f);
  if (y0 + diag > (float)H_) y0 = (float)H_ - diag;
  if (x0 + diag > (float)W_) x0 = (float)W_ - diag;
  float y0i = floorf(y0), x0i = floorf(x0);
  float phi = fmaxf(floorf(ps), 1.0f);
  float diagi = floorf(diag);
  float validf = ((phi * phi) > 60.0f) ? 1.0f : 0.0f;
  float c = (diagi - 1.0f) * 0.5f;
  float top = floorf((diagi - phi) * 0.5f);

  float* P = params + t * 16;
  P[0] = y0i; P[1] = x0i; P[2] = diagi; P[3] = phi;
  P[4] = c;
  P[5] = (float)cos((double)angle);
  P[6] = (float)sin((double)angle);
  P[7] = top;
  P[8] = bright; P[9] = (float)PH_ / phi; P[10] = 0.0f; P[11] = validf;
  P[12] = __uint_as_float(k2.x); P[13] = __uint_as_float(k2.y); P[14] = 0.0f; P[15] = 0.0f;
}

// ---------------- per-image means (deterministic partials) ----------------
__global__ __launch_bounds__(256) void reduce_kernel(
    const float* __restrict__ images, const float* __restrict__ patch,
    const float* __restrict__ wb, double* __restrict__ partials) {
  int b = blockIdx.y, j = blockIdx.x, t = threadIdx.x;
  const fx4* img4 = (const fx4*)(images + (size_t)b * IMG_ELEMS);
  double s = 0.0;
  for (int i = j * 256 + t; i < IMG_F4; i += 64 * 256) {
    fx4 v = img4[i];
    s += (double)v.x + (double)v.y + (double)v.z + (double)v.w;
  }
  float w0 = wb[b*8+0], w1 = wb[b*8+1], w2 = wb[b*8+2];
  float b0 = wb[b*8+3], b1 = wb[b*8+4], b2 = wb[b*8+5];
  double sp = 0.0;
  for (int i = j * 256 + t; i < PATCH_ELEMS; i += 64 * 256) {
    int q = i / 3; int ch = i - q * 3;
    float wv = (ch == 0) ? w0 : ((ch == 1) ? w1 : w2);
    float bv = (ch == 0) ? b0 : ((ch == 1) ? b1 : b2);
    float pv = fminf(fmaxf(wv * patch[i] + bv, -1.0f), 1.0f);
    sp += (double)pv;
  }
  __shared__ double sh[256];
  sh[t] = s; __syncthreads();
  for (int o = 128; o > 0; o >>= 1) { if (t < o) sh[t] += sh[t + o]; __syncthreads(); }
  if (t == 0) partials[((size_t)b * 64 + j) * 2 + 0] = sh[0];
  __syncthreads();
  sh[t] = sp; __syncthreads();
  for (int o = 128; o > 0; o >>= 1) { if (t < o) sh[t] += sh[t + o]; __syncthreads(); }
  if (t == 0) partials[((size_t)b * 64 + j) * 2 + 1] = sh[0];
}

// ---------------- main compose: 4 pixels per thread, float4 I/O ----------------
__global__ __launch_bounds__(256) void main_kernel(
    const float* __restrict__ images, const float* __restrict__ patch,
    const float* __restrict__ params, const float* __restrict__ wb,
    const double* __restrict__ partials, float* __restrict__ out) {
  __shared__ float sP[N_ * 16];
  __shared__ float sWB[6];
  __shared__ double sRed[64];
  __shared__ float sD;
  int b = blockIdx.y;
  int tid = threadIdx.x;
  if (tid < N_ * 16) sP[tid] = params[b * N_ * 16 + tid];
  if (tid < 6) sWB[tid] = wb[b * 8 + tid];
  // fused finalize: mean(img) - mean(clipped patch) for image b
  if (tid < 64) {
    sRed[tid] = partials[((size_t)b * 64 + tid) * 2 + 0];
  }
  __syncthreads();
  if (tid < 32) { sRed[tid] += sRed[tid + 32]; }
  __syncthreads();
  if (tid == 0) {
    double si = 0.0;
    for (int j = 0; j < 32; j++) si += sRed[j];
    double sp = 0.0;
    for (int j = 0; j < 64; j++) sp += partials[((size_t)b * 64 + j) * 2 + 1];
    sD = (float)(si / (double)IMG_ELEMS) - (float)(sp / (double)PATCH_ELEMS);
  }
  __syncthreads();

  int g = blockIdx.x * 256 + tid;        // pixel-group id, 4 px/group
  int p0 = g * 4;                        // first pixel (same row: 4 | 640)
  int y = p0 / W_;
  int x0p = p0 - y * W_;
  size_t base = ((size_t)b * (H_ * W_) + (size_t)p0) * 3;   // 16B aligned
  const fx4* in4 = (const fx4*)(images + base);
  fx4 L0 = in4[0], L1 = in4[1], L2 = in4[2];
  float pix[12];
  pix[0]=L0.x; pix[1]=L0.y; pix[2]=L0.z; pix[3]=L0.w;
  pix[4]=L1.x; pix[5]=L1.y; pix[6]=L1.z; pix[7]=L1.w;
  pix[8]=L2.x; pix[9]=L2.y; pix[10]=L2.z; pix[11]=L2.w;
  float img[12], mk[12];
#pragma unroll
  for (int i = 0; i < 12; i++) { img[i] = pix[i]; mk[i] = 0.0f; }
  float dsh = sD;
  float yf = (float)y;

#pragma unroll
  for (int j = 0; j < 4; j++) {
    float xf = (float)(x0p + j);
    float* oj = pix + j * 3;
    float* ij = img + j * 3;
    float* mj = mk + j * 3;
    for (int n = 0; n < N_; n++) {
      const float* P = sP + n * 16;
      if (P[11] == 0.0f) continue;
      float u = yf - P[0];
      float v = xf - P[1];
      float diagi = P[2];
      if (!(u >= 0.0f && v >= 0.0f && u < diagi && v < diagi)) continue;
      float phi = P[3], c = P[4], ca = P[5], sa = P[6], top = P[7], bright = P[8], sph = P[9];
      float t1 = u - c, t2 = v - c;
      float su = c + ca * t1 - sa * t2;
      float sv = c + sa * t1 + ca * t2;
      float py = su - top;
      float px = sv - top;
      bool vsrc = (py >= 0.0f) && (py <= phi - 1.0f) && (px >= 0.0f) && (px <= phi - 1.0f);
      if (vsrc) {
        float sy = (py + 0.5f) * sph - 0.5f;
        float sx = (px + 0.5f) * sph - 0.5f;
        float fy = floorf(sy), fx = floorf(sx);
        float wy = sy - fy, wxv = sx - fx;
        int iy0 = min(max((int)fy, 0), PH_ - 1);
        int iy1 = min(iy0 + 1, PH_ - 1);
        int ix0 = min(max((int)fx, 0), PW_ - 1);
        int ix1 = min(ix0 + 1, PW_ - 1);
        int o00 = (iy0 * PW_ + ix0) * 3;
        int o01 = (iy0 * PW_ + ix1) * 3;
        int o10 = (iy1 * PW_ + ix0) * 3;
        int o11 = (iy1 * PW_ + ix1) * 3;
        uint32_t k2a = __float_as_uint(P[12]);
        uint32_t k2b = __float_as_uint(P[13]);
        float omwy = 1.0f - wy, omwx = 1.0f - wxv;
        int nbase = (p0 + j) * 3;
#pragma unroll
        for (int ch = 0; ch < 3; ch++) {
          float wv = sWB[ch], bv = sWB[3 + ch];
          float a00 = fminf(fmaxf(wv * patch[o00 + ch] + bv, -1.0f), 1.0f);
          float a01 = fminf(fmaxf(wv * patch[o01 + ch] + bv, -1.0f), 1.0f);
          float a10 = fminf(fmaxf(wv * patch[o10 + ch] + bv, -1.0f), 1.0f);
          float a11 = fminf(fmaxf(wv * patch[o11 + ch] + bv, -1.0f), 1.0f);
          a00 = fminf(fmaxf(a00 + dsh, -1.0f), 1.0f);
          a01 = fminf(fmaxf(a01 + dsh, -1.0f), 1.0f);
          a10 = fminf(fmaxf(a10 + dsh, -1.0f), 1.0f);
          a11 = fminf(fmaxf(a11 + dsh, -1.0f), 1.0f);
          float samp = ((a00 * omwy) * omwx) + ((a01 * omwy) * wxv)
                     + ((a10 * wy) * omwx) + ((a11 * wy) * wxv);
          uint32_t bits = rb32(k2a, k2b, (uint32_t)(nbase + ch));
          float nz = fmaxf(-0.1f, u01f(bits) * (0.1f - (-0.1f)) + (-0.1f));
          float imv = fminf(fmaxf((samp + nz) + bright, -1.0f), 1.0f);
          ij[ch] = imv;
          mj[ch] = oj[ch] - imv;
        }
      } else {
#pragma unroll
        for (int ch = 0; ch < 3; ch++) mj[ch] = oj[ch] - ij[ch];
      }
    }
  }
  size_t moff = (size_t)B_ * (H_ * W_) * 3;
  fx4* oi4 = (fx4*)(out + base);
  fx4* om4 = (fx4*)(out + moff + base);
  fx4 S0 = {img[0], img[1], img[2],  img[3]};
  fx4 S1 = {img[4], img[5], img[6],  img[7]};
  fx4 S2 = {img[8], img[9], img[10], img[11]};
  fx4 M0 = {mk[0], mk[1], mk[2],  mk[3]};
  fx4 M1 = {mk[4], mk[5], mk[6],  mk[7]};
  fx4 M2 = {mk[8], mk[9], mk[10], mk[11]};
  __builtin_nontemporal_store(S0, oi4 + 0);
  __builtin_nontemporal_store(S1, oi4 + 1);
  __builtin_nontemporal_store(S2, oi4 + 2);
  __builtin_nontemporal_store(M0, om4 + 0);
  __builtin_nontemporal_store(M1, om4 + 1);
  __builtin_nontemporal_store(M2, om4 + 2);
}

extern "C" void kernel_launch(void* const* d_in, const int* in_sizes, int n_in,
                              void* d_out, int out_size, void* d_ws, size_t ws_size,
                              hipStream_t stream) {
  const float* boxes  = (const float*)d_in[0];
  const float* images = (const float*)d_in[1];
  const float* patch  = (const float*)d_in[2];
  const float* scale  = (const float*)d_in[3];
  float* out = (float*)d_out;

  // ws layout: [0,16384) box params (256*16 f32); [16384,16896) per-image w/b (16*8 f32);
  //            [20480,36864) partial sums (16*64*2 f64)
  float* params = (float*)d_ws;
  float* wb     = params + B_ * N_ * 16;
  double* partials = (double*)((char*)d_ws + 20480);

  setup_kernel<<<1, 256, 0, stream>>>(boxes, scale, params, wb);
  reduce_kernel<<<dim3(64, B_), 256, 0, stream>>>(images, patch, wb, partials);
  main_kernel<<<dim3((H_ * W_) / (256 * 4), B_), 256, 0, stream>>>(images, patch, params, wb, partials, out);
}

// Round 6
// 327.134 us; speedup vs baseline: 1.0047x; 1.0047x over previous
//
#include <hip/hip_runtime.h>
#include <stdint.h>
#include <math.h>

#define B_ 16
#define N_ 16
#define H_ 640
#define W_ 640
#define PH_ 300
#define PW_ 300

#define IMG_ELEMS (H_*W_*3)        // 1228800
#define IMG_F4    (IMG_ELEMS/4)    // 307200
#define PATCH_ELEMS (PH_*PW_*3)    // 270000

typedef float fx4 __attribute__((ext_vector_type(4)));

// ---------------- JAX Threefry-2x32-20, bit-exact ----------------
__device__ __forceinline__ uint2 tf2x32(uint32_t k0, uint32_t k1, uint32_t x0, uint32_t x1) {
  uint32_t k2 = k0 ^ k1 ^ 0x1BD11BDAu;
#define TFR(r) x0 += x1; x1 = (x1 << (r)) | (x1 >> (32 - (r))); x1 ^= x0;
  x0 += k0; x1 += k1;
  TFR(13) TFR(15) TFR(26) TFR(6)
  x0 += k1; x1 += k2 + 1u;
  TFR(17) TFR(29) TFR(16) TFR(24)
  x0 += k2; x1 += k0 + 2u;
  TFR(13) TFR(15) TFR(26) TFR(6)
  x0 += k0; x1 += k1 + 3u;
  TFR(17) TFR(29) TFR(16) TFR(24)
  x0 += k1; x1 += k2 + 4u;
  TFR(13) TFR(15) TFR(26) TFR(6)
  x0 += k2; x1 += k0 + 5u;
#undef TFR
  return make_uint2(x0, x1);
}

// jax_threefry_partitionable=True (default since jax 0.4.30):
//  - split(key, n):   key_i = (out.x, out.y) of tf(key, (0, i))
//  - random_bits(key, 32, shape): elem_i = out.x ^ out.y of tf(key, (0, i))
__device__ __forceinline__ uint32_t rb32(uint32_t k0, uint32_t k1, uint32_t i) {
  uint2 o = tf2x32(k0, k1, 0u, i);
  return o.x ^ o.y;
}

__device__ __forceinline__ float u01f(uint32_t bits) {
  return __uint_as_float((bits >> 9) | 0x3F800000u) - 1.0f;
}

// XLA f32 ErfInv (Giles polynomial) — matches lax.erf_inv
__device__ __forceinline__ float erfinv32(float x) {
  float w = -log1pf(-x * x);
  float p;
  if (w < 5.0f) {
    w = w - 2.5f;
    p = 2.81022636e-08f;
    p = fmaf(p, w, 3.43273939e-07f);
    p = fmaf(p, w, -3.5233877e-06f);
    p = fmaf(p, w, -4.39150654e-06f);
    p = fmaf(p, w, 0.00021858087f);
    p = fmaf(p, w, -0.00125372503f);
    p = fmaf(p, w, -0.00417768164f);
    p = fmaf(p, w, 0.246640727f);
    p = fmaf(p, w, 1.50140941f);
  } else {
    w = sqrtf(w) - 3.0f;
    p = -0.000200214257f;
    p = fmaf(p, w, 0.000100950558f);
    p = fmaf(p, w, 0.00134934322f);
    p = fmaf(p, w, -0.00367342844f);
    p = fmaf(p, w, 0.00573950773f);
    p = fmaf(p, w, -0.0076224613f);
    p = fmaf(p, w, 0.00943887047f);
    p = fmaf(p, w, 1.00167406f);
    p = fmaf(p, w, 2.83297682f);
  }
  return p * x;
}

// jax.random.normal: u ~ uniform(nextafter(-1,0), 1), sqrt(2)*erfinv(u)
__device__ __forceinline__ float jnormal(uint32_t bits) {
  float lo = __uint_as_float(0xBF7FFFFFu);  // nextafterf(-1,0)
  float span = 1.0f - lo;                   // rounds to 2.0f, same as XLA
  float u = fmaxf(lo, u01f(bits) * span + lo);
  return 1.4142135623730951f * erfinv32(u);
}

// ---------------- per-(image,box) parameters ----------------
// params[t*16]: 0 y0i, 1 x0i, 2 diagi, 3 phi, 4 c, 5 ca, 6 sa, 7 top,
//               8 bright, 9 300/phi, 10 unused, 11 valid, 12 k2a, 13 k2b
__global__ void setup_kernel(const float* __restrict__ boxes, const float* __restrict__ scale_p,
                             float* __restrict__ params, float* __restrict__ wb) {
  int t = threadIdx.x;
  if (t >= B_*N_) return;
  int b = t >> 4, n = t & 15;
  uint2 kb = tf2x32(0u, 42u, 0u, (uint32_t)b);
  uint2 kw  = tf2x32(kb.x, kb.y, 0u, 0u);
  uint2 kbk = tf2x32(kb.x, kb.y, 0u, 1u);
  uint2 kl  = tf2x32(kb.x, kb.y, 0u, 2u);
  if (n == 0) {
    wb[b*8+0] = jnormal(rb32(kw.x,  kw.y,  0u)) * 0.1f + 0.5f;
    wb[b*8+1] = jnormal(rb32(kw.x,  kw.y,  1u)) * 0.1f + 0.5f;
    wb[b*8+2] = jnormal(rb32(kw.x,  kw.y,  2u)) * 0.1f + 0.5f;
    wb[b*8+3] = jnormal(rb32(kbk.x, kbk.y, 0u)) * 0.01f;
    wb[b*8+4] = jnormal(rb32(kbk.x, kbk.y, 1u)) * 0.01f;
    wb[b*8+5] = jnormal(rb32(kbk.x, kbk.y, 2u)) * 0.01f;
  }
  uint2 kk = tf2x32(kl.x, kl.y, 0u, (uint32_t)n);
  uint2 k1 = tf2x32(kk.x, kk.y, 0u, 0u);
  uint2 k2 = tf2x32(kk.x, kk.y, 0u, 1u);
  uint2 k3 = tf2x32(kk.x, kk.y, 0u, 2u);
  const float MA = (float)(20.0 * 3.14159265358979323846 / 180.0);
  float angle  = fmaxf(-MA,   u01f(rb32(k1.x, k1.y, 0u)) * (MA - (-MA)) + (-MA));
  float bright = fmaxf(-0.3f, u01f(rb32(k3.x, k3.y, 0u)) * (0.3f - (-0.3f)) + (-0.3f));

  const float* bx = boxes + (size_t)t * 4;
  float ymin = bx[0], xmin = bx[1], ymax = bx[2], xmax = bx[3];
  float sc = scale_p[0];
  float h = ymax - ymin, ww = xmax - xmin;
  float longer = fmaxf(h, ww);
  float ps = floorf(longer * sc);
  float diag = fminf(sqrtf(2.0f) * ps, (float)W_);
  float oy = ymin + h * 0.5f;
  float ox = xmin + ww * 0.5f;
  float y0 = fmaxf(oy - diag * 0.5f, 0.0f);
  float x0 = fmaxf(ox - diag * 0.5f, 0.0f);
  if (y0 + diag > (float)H_) y0 = (float)H_ - diag;
  if (x0 + diag > (float)W_) x0 = (float)W_ - diag;
  float y0i = floorf(y0), x0i = floorf(x0);
  float phi = fmaxf(floorf(ps), 1.0f);
  float diagi = floorf(diag);
  float validf = ((phi * phi) > 60.0f) ? 1.0f : 0.0f;
  float c = (diagi - 1.0f) * 0.5f;
  float top = floorf((diagi - phi) * 0.5f);

  float* P = params + t * 16;
  P[0] = y0i; P[1] = x0i; P[2] = diagi; P[3] = phi;
  P[4] = c;
  P[5] = (float)cos((double)angle);
  P[6] = (float)sin((double)angle);
  P[7] = top;
  P[8] = bright; P[9] = (float)PH_ / phi; P[10] = 0.0f; P[11] = validf;
  P[12] = __uint_as_float(k2.x); P[13] = __uint_as_float(k2.y); P[14] = 0.0f; P[15] = 0.0f;
}

// ---------------- fused stream copy + per-image mean partials ----------------
// out_img = images, out_mask = 0 (box regions get overwritten by compose_kernel)
__global__ __launch_bounds__(256) void copy_reduce_kernel(
    const float* __restrict__ images, const float* __restrict__ patch,
    const float* __restrict__ wb, double* __restrict__ partials,
    float* __restrict__ out) {
  int b = blockIdx.y, j = blockIdx.x, t = threadIdx.x;
  const fx4* img4 = (const fx4*)(images + (size_t)b * IMG_ELEMS);
  fx4* oi4 = (fx4*)(out + (size_t)b * IMG_ELEMS);
  fx4* om4 = (fx4*)(out + (size_t)B_ * IMG_ELEMS + (size_t)b * IMG_ELEMS);
  const fx4 zero = {0.0f, 0.0f, 0.0f, 0.0f};
  double s = 0.0;
  for (int i = j * 256 + t; i < IMG_F4; i += 64 * 256) {
    fx4 v = img4[i];
    s += (double)v.x + (double)v.y + (double)v.z + (double)v.w;
    __builtin_nontemporal_store(v, oi4 + i);
    __builtin_nontemporal_store(zero, om4 + i);
  }
  float w0 = wb[b*8+0], w1 = wb[b*8+1], w2 = wb[b*8+2];
  float b0 = wb[b*8+3], b1 = wb[b*8+4], b2 = wb[b*8+5];
  double sp = 0.0;
  for (int i = j * 256 + t; i < PATCH_ELEMS; i += 64 * 256) {
    int q = i / 3; int ch = i - q * 3;
    float wv = (ch == 0) ? w0 : ((ch == 1) ? w1 : w2);
    float bv = (ch == 0) ? b0 : ((ch == 1) ? b1 : b2);
    float pv = fminf(fmaxf(wv * patch[i] + bv, -1.0f), 1.0f);
    sp += (double)pv;
  }
  __shared__ double sh[256];
  sh[t] = s; __syncthreads();
  for (int o = 128; o > 0; o >>= 1) { if (t < o) sh[t] += sh[t + o]; __syncthreads(); }
  if (t == 0) partials[((size_t)b * 64 + j) * 2 + 0] = sh[0];
  __syncthreads();
  sh[t] = sp; __syncthreads();
  for (int o = 128; o > 0; o >>= 1) { if (t < o) sh[t] += sh[t + o]; __syncthreads(); }
  if (t == 0) partials[((size_t)b * 64 + j) * 2 + 1] = sh[0];
}

// ---------------- box compose: 16x16 tiles, last-valid-box-wins ----------------
// Derivation from the scan: final_img = imv(last box with sel & valid_src) else orig;
// final_mask = orig - final_img (0 where no valid box covers). So only valid-patch
// pixels need writes; copy_reduce_kernel already wrote everything else.
__global__ __launch_bounds__(256) void compose_kernel(
    const float* __restrict__ images, const float* __restrict__ patch,
    const float* __restrict__ params, const float* __restrict__ wb,
    const double* __restrict__ partials, float* __restrict__ out) {
  __shared__ float sP[N_ * 16];
  __shared__ float sWB[6];
  __shared__ double sRed[64];
  __shared__ float sD;
  int b = blockIdx.z;
  int tid = threadIdx.x;
  if (tid < N_ * 16) sP[tid] = params[b * N_ * 16 + tid];
  if (tid < 6) sWB[tid] = wb[b * 8 + tid];
  __syncthreads();

  // tile-level box intersection mask (uniform across block)
  int tx0 = blockIdx.x * 16;
  int ty0 = blockIdx.y * 16;
  unsigned bmask = 0;
#pragma unroll
  for (int n = 0; n < N_; n++) {
    const float* P = sP + n * 16;
    if (P[11] == 0.0f) continue;
    int by0 = (int)P[0], bx0 = (int)P[1], d = (int)P[2];
    if (bx0 < tx0 + 16 && bx0 + d > tx0 && by0 < ty0 + 16 && by0 + d > ty0)
      bmask |= (1u << n);
  }
  if (bmask == 0) return;

  // fused finalize: d = mean(img) - mean(clipped patch)
  if (tid < 64) sRed[tid] = partials[((size_t)b * 64 + tid) * 2 + 0];
  __syncthreads();
  if (tid < 32) sRed[tid] += sRed[tid + 32];
  __syncthreads();
  if (tid == 0) {
    double si = 0.0;
    for (int j = 0; j < 32; j++) si += sRed[j];
    double sp = 0.0;
    for (int j = 0; j < 64; j++) sp += partials[((size_t)b * 64 + j) * 2 + 1];
    sD = (float)(si / (double)IMG_ELEMS) - (float)(sp / (double)PATCH_ELEMS);
  }
  __syncthreads();
  float dsh = sD;

  int x = tx0 + (tid & 15);
  int y = ty0 + (tid >> 4);
  float xf = (float)x, yf = (float)y;
  int p = y * W_ + x;

  // scan boxes last-to-first; first valid hit wins
  for (int n = N_ - 1; n >= 0; n--) {
    if (!(bmask & (1u << n))) continue;
    const float* P = sP + n * 16;
    float u = yf - P[0];
    float v = xf - P[1];
    float diagi = P[2];
    if (!(u >= 0.0f && v >= 0.0f && u < diagi && v < diagi)) continue;
    float phi = P[3], c = P[4], ca = P[5], sa = P[6], top = P[7], bright = P[8], sph = P[9];
    float t1 = u - c, t2 = v - c;
    float su = c + ca * t1 - sa * t2;
    float sv = c + sa * t1 + ca * t2;
    float py = su - top;
    float px = sv - top;
    if (!((py >= 0.0f) && (py <= phi - 1.0f) && (px >= 0.0f) && (px <= phi - 1.0f))) continue;

    float sy = (py + 0.5f) * sph - 0.5f;
    float sx = (px + 0.5f) * sph - 0.5f;
    float fy = floorf(sy), fx = floorf(sx);
    float wy = sy - fy, wxv = sx - fx;
    int iy0 = min(max((int)fy, 0), PH_ - 1);
    int iy1 = min(iy0 + 1, PH_ - 1);
    int ix0 = min(max((int)fx, 0), PW_ - 1);
    int ix1 = min(ix0 + 1, PW_ - 1);
    int o00 = (iy0 * PW_ + ix0) * 3;
    int o01 = (iy0 * PW_ + ix1) * 3;
    int o10 = (iy1 * PW_ + ix0) * 3;
    int o11 = (iy1 * PW_ + ix1) * 3;
    uint32_t k2a = __float_as_uint(P[12]);
    uint32_t k2b = __float_as_uint(P[13]);
    float omwy = 1.0f - wy, omwx = 1.0f - wxv;
    size_t base = ((size_t)b * (H_ * W_) + (size_t)p) * 3;
    size_t moff = (size_t)B_ * IMG_ELEMS;
#pragma unroll
    for (int ch = 0; ch < 3; ch++) {
      float wv = sWB[ch], bv = sWB[3 + ch];
      float a00 = fminf(fmaxf(wv * patch[o00 + ch] + bv, -1.0f), 1.0f);
      float a01 = fminf(fmaxf(wv * patch[o01 + ch] + bv, -1.0f), 1.0f);
      float a10 = fminf(fmaxf(wv * patch[o10 + ch] + bv, -1.0f), 1.0f);
      float a11 = fminf(fmaxf(wv * patch[o11 + ch] + bv, -1.0f), 1.0f);
      a00 = fminf(fmaxf(a00 + dsh, -1.0f), 1.0f);
      a01 = fminf(fmaxf(a01 + dsh, -1.0f), 1.0f);
      a10 = fminf(fmaxf(a10 + dsh, -1.0f), 1.0f);
      a11 = fminf(fmaxf(a11 + dsh, -1.0f), 1.0f);
      float samp = ((a00 * omwy) * omwx) + ((a01 * omwy) * wxv)
                 + ((a10 * wy) * omwx) + ((a11 * wy) * wxv);
      uint32_t bits = rb32(k2a, k2b, (uint32_t)(p * 3 + ch));
      float nz = fmaxf(-0.1f, u01f(bits) * (0.1f - (-0.1f)) + (-0.1f));
      float imv = fminf(fmaxf((samp + nz) + bright, -1.0f), 1.0f);
      float orig = images[base + ch];
      out[base + ch] = imv;
      out[moff + base + ch] = orig - imv;
    }
    return;  // last valid box wins — done with this pixel
  }
}

extern "C" void kernel_launch(void* const* d_in, const int* in_sizes, int n_in,
                              void* d_out, int out_size, void* d_ws, size_t ws_size,
                              hipStream_t stream) {
  const float* boxes  = (const float*)d_in[0];
  const float* images = (const float*)d_in[1];
  const float* patch  = (const float*)d_in[2];
  const float* scale  = (const float*)d_in[3];
  float* out = (float*)d_out;

  // ws layout: [0,16384) box params (256*16 f32); [16384,16896) per-image w/b (16*8 f32);
  //            [20480,36864) partial sums (16*64*2 f64)
  float* params = (float*)d_ws;
  float* wb     = params + B_ * N_ * 16;
  double* partials = (double*)((char*)d_ws + 20480);

  setup_kernel<<<1, 256, 0, stream>>>(boxes, scale, params, wb);
  copy_reduce_kernel<<<dim3(64, B_), 256, 0, stream>>>(images, patch, wb, partials, out);
  compose_kernel<<<dim3(W_ / 16, H_ / 16, B_), 256, 0, stream>>>(images, patch, params, wb, partials, out);
}